// Round 1
// baseline (91.681 us; speedup 1.0000x reference)
//
#include <hip/hip_runtime.h>
#include <hip/hip_bf16.h>
#include <math.h>

#define BINS 10
#define K1_BLOCKS 1024
#define K1_THREADS 256
#define LSTRIDE 11   // 10 bins padded to 11 floats (odd stride -> conflict-free-ish)

// Kernel 1: per-block partial histograms of {count, sum(bce)} per bin.
// partial layout: rows 0..9  = counts  (row b, 1024 cols = blocks)
//                 rows 10..19 = bce sums
__global__ __launch_bounds__(K1_THREADS) void ghm_partial(
    const int*   __restrict__ labels,
    const float* __restrict__ logits,
    const float* __restrict__ weights,
    float*       __restrict__ partial,
    int n4, int n)
{
    __shared__ float lds_cnt[K1_THREADS * LSTRIDE];
    __shared__ float lds_sum[K1_THREADS * LSTRIDE];
    const int tid = threadIdx.x;

    #pragma unroll
    for (int b = 0; b < BINS; ++b) {
        lds_cnt[tid * LSTRIDE + b] = 0.0f;
        lds_sum[tid * LSTRIDE + b] = 0.0f;
    }
    // no barrier needed: each thread touches only its own slots until the reduce

    const int4*   lab4 = (const int4*)labels;
    const float4* log4 = (const float4*)logits;
    const float4* w4   = (const float4*)weights;

    const int stride = gridDim.x * blockDim.x;
    for (int i = blockIdx.x * blockDim.x + tid; i < n4; i += stride) {
        int4   lb = lab4[i];
        float4 xv = log4[i];
        float4 wv = w4[i];
        #pragma unroll
        for (int c = 0; c < 4; ++c) {
            int   y = ((const int*)&lb)[c];
            float x = ((const float*)&xv)[c];
            float w = ((const float*)&wv)[c];
            float xs = (y == 1) ? -x : x;
            float a  = __expf(-fabsf(xs));          // e^{-|xs|}, in (0,1]
            float r  = 1.0f / (1.0f + a);
            float pn = (xs >= 0.0f) ? r : a * r;    // sigmoid(xs) == p_norm
            int bin  = (int)(pn * 10.0f);           // pn>0, trunc == floor
            bin = bin > (BINS - 1) ? (BINS - 1) : bin;
            float bce   = fmaxf(xs, 0.0f) + __logf(1.0f + a);  // softplus(xs)
            float valid = (w > 0.0f) ? 1.0f : 0.0f;
            lds_cnt[tid * LSTRIDE + bin] += valid;
            lds_sum[tid * LSTRIDE + bin] += bce * valid;
        }
    }

    // scalar tail (n % 4 elements), handled by block 0
    int rem_start = n4 * 4;
    if (blockIdx.x == 0 && tid < (n - rem_start)) {
        int   idx = rem_start + tid;
        int   y = labels[idx];
        float x = logits[idx];
        float w = weights[idx];
        float xs = (y == 1) ? -x : x;
        float a  = __expf(-fabsf(xs));
        float r  = 1.0f / (1.0f + a);
        float pn = (xs >= 0.0f) ? r : a * r;
        int bin  = (int)(pn * 10.0f);
        bin = bin > (BINS - 1) ? (BINS - 1) : bin;
        float bce   = fmaxf(xs, 0.0f) + __logf(1.0f + a);
        float valid = (w > 0.0f) ? 1.0f : 0.0f;
        lds_cnt[tid * LSTRIDE + bin] += valid;
        lds_sum[tid * LSTRIDE + bin] += bce * valid;
    }

    __syncthreads();

    // tree-reduce across the 256 threads
    for (int off = K1_THREADS / 2; off > 0; off >>= 1) {
        if (tid < off) {
            #pragma unroll
            for (int b = 0; b < BINS; ++b) {
                lds_cnt[tid * LSTRIDE + b] += lds_cnt[(tid + off) * LSTRIDE + b];
                lds_sum[tid * LSTRIDE + b] += lds_sum[(tid + off) * LSTRIDE + b];
            }
        }
        __syncthreads();
    }

    if (tid < BINS) {
        partial[tid * K1_BLOCKS + blockIdx.x]          = lds_cnt[tid];
        partial[(BINS + tid) * K1_BLOCKS + blockIdx.x] = lds_sum[tid];
    }
}

// Kernel 2: reduce 1024 partial columns, finalize scalar.
__global__ __launch_bounds__(1024) void ghm_final(
    const float* __restrict__ partial, float* __restrict__ out)
{
    const int tid = threadIdx.x;
    float acc[2 * BINS];
    #pragma unroll
    for (int b = 0; b < 2 * BINS; ++b)
        acc[b] = partial[b * K1_BLOCKS + tid];   // coalesced row loads

    // 64-lane shuffle tree
    #pragma unroll
    for (int off = 32; off > 0; off >>= 1) {
        #pragma unroll
        for (int b = 0; b < 2 * BINS; ++b)
            acc[b] += __shfl_down(acc[b], off);
    }

    __shared__ float red[16][2 * BINS];
    const int wave = tid >> 6, lane = tid & 63;
    if (lane == 0) {
        #pragma unroll
        for (int b = 0; b < 2 * BINS; ++b) red[wave][b] = acc[b];
    }
    __syncthreads();

    if (tid == 0) {
        float cnt[BINS], s[BINS];
        #pragma unroll
        for (int b = 0; b < BINS; ++b) { cnt[b] = 0.0f; s[b] = 0.0f; }
        for (int wv = 0; wv < 16; ++wv) {
            #pragma unroll
            for (int b = 0; b < BINS; ++b) {
                cnt[b] += red[wv][b];
                s[b]   += red[wv][BINS + b];
            }
        }
        float n = 0.0f, res = 0.0f;
        #pragma unroll
        for (int b = 0; b < BINS; ++b) {
            if (cnt[b] > 0.0f) {
                n   += 1.0f;
                res += s[b] / fmaxf(cnt[b], 1.0f);
            }
        }
        if (n > 0.0f) res /= n;   // total_num cancels exactly in the algebra
        out[0] = res;
    }
}

extern "C" void kernel_launch(void* const* d_in, const int* in_sizes, int n_in,
                              void* d_out, int out_size, void* d_ws, size_t ws_size,
                              hipStream_t stream) {
    const int*   labels  = (const int*)d_in[0];
    const float* logits  = (const float*)d_in[1];
    const float* weights = (const float*)d_in[2];
    float* out     = (float*)d_out;
    float* partial = (float*)d_ws;   // needs 2*BINS*K1_BLOCKS*4 = 80 KiB

    const int n  = in_sizes[0];
    const int n4 = n / 4;

    ghm_partial<<<K1_BLOCKS, K1_THREADS, 0, stream>>>(labels, logits, weights, partial, n4, n);
    ghm_final<<<1, 1024, 0, stream>>>(partial, out);
}